// Round 1
// baseline (571.318 us; speedup 1.0000x reference)
//
#include <hip/hip_runtime.h>

#define BT (256*512)   // 131072 positions
#define HID 128
#define EMB 64
#define CH 32          // scan chunk: steps staged per LDS refill

typedef float f32x2 __attribute__((ext_vector_type(2)));

__device__ __forceinline__ float fast_tanh(float x) {   // 1 - 2/(exp(2x)+1)
    float e = __expf(2.f * x);
    return 1.f - __fdividef(2.f, e + 1.f);
}

// packed fp32 FMA (VOP3P, full 157-TF rate): d.lo+=a.lo*b.lo, d.hi+=a.hi*b.hi
#define PKFMA(d, a, b) asm("v_pk_fma_f32 %0, %1, %2, %0" : "+v"(d) : "v"(a), "v"(b))
// butterfly add across quad lanes via DPP quad_perm (ctrl compile-time)
#define DPPADD(v, ctrl) ((v) + __int_as_float(__builtin_amdgcn_mov_dpp(__float_as_int(v), (ctrl), 0xf, 0xf, false)))
// lane l <-> lane l^4 (ds_swizzle BitMode: xor=4, and=0x1f)
#define SWZ4(v) __int_as_float(__builtin_amdgcn_ds_swizzle(__float_as_int(v), 0x101F))

__device__ __forceinline__ float mux4(int k, float x0, float x1, float x2, float x3) {
    float t0 = (k & 1) ? x1 : x0;
    float t1 = (k & 1) ? x3 : x2;
    return (k & 2) ? t1 : t0;
}

// ---------------- kernel 1: embedding gather + layer-1 input GEMM (unchanged)
__global__ __launch_bounds__(256)
__attribute__((amdgpu_waves_per_eu(1, 2)))
void k_embed_pre1(
    const int* __restrict__ x, const float* __restrict__ emb,
    const float* __restrict__ Wih1, const float* __restrict__ bih1,
    const float* __restrict__ bhh1, float* __restrict__ pre1)
{
    __shared__ float sA[32][128];
    __shared__ float sW[32][132];
    __shared__ int stok[128];
    const int tid = threadIdx.x;
    const int base = blockIdx.x * 128;
    const int tx = tid & 15, ty = tid >> 4;
    const int ox = tx * 8, py = ty * 8;
    const int pl = tid & 127, half = tid >> 7;
    if (tid < 128) stok[tid] = x[base + tid];
    float acc[8][8];
#pragma unroll
    for (int p = 0; p < 8; ++p)
#pragma unroll
        for (int o = 0; o < 8; ++o) acc[p][o] = 0.f;
    __syncthreads();
    const float4* ws = (const float4*)(Wih1 + (size_t)pl * EMB + half * 16);
    const float4* as = (const float4*)(emb + (size_t)stok[pl] * EMB + half * 16);
    float4 qw[2][4], qe[2][4];
#pragma unroll
    for (int kc = 0; kc < 2; ++kc)
#pragma unroll
        for (int k = 0; k < 4; ++k) {
            qw[kc][k] = ws[kc * 8 + k];
            qe[kc][k] = as[kc * 8 + k];
        }
    for (int kc = 0; kc < 2; ++kc) {
        {
            const int jb = half * 16;
#pragma unroll
            for (int k = 0; k < 4; ++k) {
                float4 q = qw[kc][k], e = qe[kc][k];
                sW[jb + 4*k + 0][pl] = q.x; sW[jb + 4*k + 1][pl] = q.y;
                sW[jb + 4*k + 2][pl] = q.z; sW[jb + 4*k + 3][pl] = q.w;
                sA[jb + 4*k + 0][pl] = e.x; sA[jb + 4*k + 1][pl] = e.y;
                sA[jb + 4*k + 2][pl] = e.z; sA[jb + 4*k + 3][pl] = e.w;
            }
        }
        __syncthreads();
#pragma unroll 4
        for (int j = 0; j < 32; ++j) {
            float4 a0 = *(const float4*)&sA[j][py];
            float4 a1 = *(const float4*)&sA[j][py + 4];
            float4 b0 = *(const float4*)&sW[j][ox];
            float4 b1 = *(const float4*)&sW[j][ox + 4];
            float av[8] = {a0.x,a0.y,a0.z,a0.w,a1.x,a1.y,a1.z,a1.w};
            float bv[8] = {b0.x,b0.y,b0.z,b0.w,b1.x,b1.y,b1.z,b1.w};
#pragma unroll
            for (int p = 0; p < 8; ++p)
#pragma unroll
                for (int o = 0; o < 8; ++o)
                    acc[p][o] = fmaf(av[p], bv[o], acc[p][o]);
        }
        __syncthreads();
    }
    float bo[8];
#pragma unroll
    for (int o = 0; o < 8; ++o) bo[o] = bih1[ox + o] + bhh1[ox + o];
#pragma unroll
    for (int p = 0; p < 8; ++p) {
        float* cp = pre1 + (size_t)(base + py + p) * HID + ox;
        *(float4*)cp       = make_float4(acc[p][0]+bo[0], acc[p][1]+bo[1], acc[p][2]+bo[2], acc[p][3]+bo[3]);
        *(float4*)(cp + 4) = make_float4(acc[p][4]+bo[4], acc[p][5]+bo[5], acc[p][6]+bo[6], acc[p][7]+bo[7]);
    }
}

// ---------------- kernel 2: fused two-layer recurrence, 3-wave / DPP-reduce form.
// wave 0   : h1_t    = tanh(pre1[t] + Whh1 @ h1_{t-1})
// waves 1-2: h2_{t-1} = tanh(b2 + Wih2 @ h1_{t-1} + Whh2 @ h2_{t-2})   (lag-1 pipeline)
// Each lane pins 8 weight rows x 32-col K-slice in VGPRs (256 regs). K-partials are
// reduced in-wave (DPP xor1/xor2; + one ds_swizzle xor4 for the Wih2/Whh2 halves),
// so each step is: 16 ds_read_b64 + 128 v_pk_fma_f32 + reduce + tanh + 1 barrier.
__global__ __launch_bounds__(192, 1)
__attribute__((amdgpu_waves_per_eu(1, 1)))
void k_rnn_fused(
    const float* __restrict__ pre1, const float* __restrict__ Whh1,
    const float* __restrict__ Wih2, const float* __restrict__ bih2,
    const float* __restrict__ bhh2, const float* __restrict__ Whh2,
    const float* __restrict__ ln_g, const float* __restrict__ ln_b,
    const float* __restrict__ projW, const float* __restrict__ proj_b,
    const float* __restrict__ on_g, const float* __restrict__ on_b,
    float* __restrict__ out)
{
    // h buffers: [parity][layer][quarter*36 + k]. 36-word quarter stride + 144-word
    // layer stride => the 8 (layer,quarter) broadcast streams hit 8 distinct bank
    // quads {0,4,8,12,16,20,24,28} -> conflict-free ds_read_b64.
    __shared__ __align__(16) float hb[2][2][144];
    __shared__ __align__(16) float spre[CH * HID];   // staged pre1 chunk (16 KB)
    __shared__ __align__(16) float sfin[HID];

    const int bb   = blockIdx.x;
    const int tid  = threadIdx.x;
    const int wid  = tid >> 6;          // 0 = L1, 1-2 = L2
    const int lane = tid & 63;
    const int lq   = lane & 3;          // K-quarter within matrix
    const int lo4  = lane & 4;          // L2: 0 => Wih2 half, 4 => Whh2 half

    int rowbase, layer;
    const float* wsel;
    if (wid == 0) { rowbase = (lane >> 2) * 8; layer = 0; wsel = Whh1; }
    else {
        rowbase = ((wid - 1) * 8 + (lane >> 3)) * 8;
        layer = lo4 ? 1 : 0;
        wsel = lo4 ? Whh2 : Wih2;
    }
    const int own0 = rowbase + ((wid == 0) ? lq : (lane & 7));
    const int own1 = own0 + 4;          // dereferenced by wave 0 only

    // ---- pin 8 rows x 16 f32x2 of weights in VGPRs (256 regs/lane)
    f32x2 W2[8][16];
#pragma unroll
    for (int r = 0; r < 8; ++r) {
        const f32x2* src = (const f32x2*)(wsel + (size_t)(rowbase + r) * HID + lq * 32);
#pragma unroll
        for (int k = 0; k < 16; ++k) W2[r][k] = src[k];
    }
#pragma unroll
    for (int r = 0; r < 8; ++r)
#pragma unroll
        for (int k = 0; k < 16; ++k) asm volatile("" : "+v"(W2[r][k]));

    const float b2o = (wid != 0) ? (bih2[own0] + bhh2[own0]) : 0.f;

    if (tid < 144) { hb[0][0][tid] = 0.f; hb[0][1][tid] = 0.f; }

    // parity-resolved LDS pointers (even t reads hb[0], writes hb[1]; odd t flips)
    const f32x2* r_e = (const f32x2*)&hb[0][layer][lq * 36];
    const f32x2* r_o = (const f32x2*)&hb[1][layer][lq * 36];
    const int wl = (wid == 0) ? 0 : 1;
    float* w_e0 = &hb[1][wl][((own0 >> 5) * 36) + (own0 & 31)];
    float* w_o0 = &hb[0][wl][((own0 >> 5) * 36) + (own0 & 31)];
    float* w_e1 = &hb[1][0][((own1 >> 5) * 36) + (own1 & 31)];
    float* w_o1 = &hb[0][0][((own1 >> 5) * 36) + (own1 & 31)];

    const float4* gsrc = (const float4*)(pre1 + (size_t)bb * 512 * HID);
    float4* spv = (float4*)spre;
    float4 pf0, pf1, pf2, pf3, pf4, pf5;

    auto prefetch = [&](int cc) {        // 1024 float4 = one chunk; 5 sweeps + tail
        const int base = cc * 1024;
        pf0 = gsrc[base + tid];
        pf1 = gsrc[base + tid + 192];
        pf2 = gsrc[base + tid + 384];
        pf3 = gsrc[base + tid + 576];
        pf4 = gsrc[base + tid + 768];
        if (wid == 2) pf5 = gsrc[base + lane + 960];
    };

    auto do_step = [&](int t, int sic, const f32x2* __restrict__ hp,
                       float* wp0, float* wp1) {
        float pA = 0.f, pB = 0.f;
        if (wid == 0) {                              // pre1 values for my 2 rows
            pA = spre[sic * HID + own0];
            pB = spre[sic * HID + own1];
        }
        f32x2 a0={0.f,0.f}, a1={0.f,0.f}, a2={0.f,0.f}, a3={0.f,0.f},
              a4={0.f,0.f}, a5={0.f,0.f}, a6={0.f,0.f}, a7={0.f,0.f};
#pragma unroll
        for (int kk = 0; kk < 16; ++kk) {
            f32x2 hv = hp[kk];
            PKFMA(a0, hv, W2[0][kk]); PKFMA(a1, hv, W2[1][kk]);
            PKFMA(a2, hv, W2[2][kk]); PKFMA(a3, hv, W2[3][kk]);
            PKFMA(a4, hv, W2[4][kk]); PKFMA(a5, hv, W2[5][kk]);
            PKFMA(a6, hv, W2[6][kk]); PKFMA(a7, hv, W2[7][kk]);
        }
        float s0 = a0.x + a0.y, s1 = a1.x + a1.y, s2 = a2.x + a2.y, s3 = a3.x + a3.y,
              s4 = a4.x + a4.y, s5 = a5.x + a5.y, s6 = a6.x + a6.y, s7 = a7.x + a7.y;
        // quad butterfly: sum the 4 K-quarters (slot r = row rowbase+r, all quad lanes)
        s0 = DPPADD(s0, 0xB1); s1 = DPPADD(s1, 0xB1); s2 = DPPADD(s2, 0xB1); s3 = DPPADD(s3, 0xB1);
        s4 = DPPADD(s4, 0xB1); s5 = DPPADD(s5, 0xB1); s6 = DPPADD(s6, 0xB1); s7 = DPPADD(s7, 0xB1);
        s0 = DPPADD(s0, 0x4E); s1 = DPPADD(s1, 0x4E); s2 = DPPADD(s2, 0x4E); s3 = DPPADD(s3, 0x4E);
        s4 = DPPADD(s4, 0x4E); s5 = DPPADD(s5, 0x4E); s6 = DPPADD(s6, 0x4E); s7 = DPPADD(s7, 0x4E);
        if (wid == 0) {
            float v0 = mux4(lq, s0, s1, s2, s3);     // row own0 = rowbase+lq
            float v1 = mux4(lq, s4, s5, s6, s7);     // row own1 = rowbase+lq+4
            *wp0 = fast_tanh(pA + v0);
            *wp1 = fast_tanh(pB + v1);
        } else {
            float mql = mux4(lq, s0, s1, s2, s3);
            float mqh = mux4(lq, s4, s5, s6, s7);
            float m1 = lo4 ? mqh : mql;              // my row,        my matrix
            float m2 = lo4 ? mql : mqh;              // partner's row, my matrix
            float bv = b2o + m1 + SWZ4(m2);          // + my row, partner matrix
            *wp0 = (t > 0) ? fast_tanh(bv) : 0.f;    // h2_{-1} = 0
        }
    };

    prefetch(0);
    __syncthreads();                                  // hb init visible

#pragma unroll 1
    for (int c = 0; c < 512 / CH; ++c) {
        // commit prefetched chunk c, then start fetching c+1 (hides under 32 steps)
        spv[tid] = pf0; spv[tid + 192] = pf1; spv[tid + 384] = pf2;
        spv[tid + 576] = pf3; spv[tid + 768] = pf4;
        if (wid == 2) spv[lane + 960] = pf5;
        __syncthreads();
        if (c < 512 / CH - 1) prefetch(c + 1);
        const int t0 = c * CH;
#pragma unroll 1
        for (int s = 0; s < CH; s += 2) {
            do_step(t0 + s,     s,     r_e, w_e0, w_e1);
            __syncthreads();
            do_step(t0 + s + 1, s + 1, r_o, w_o0, w_o1);
            __syncthreads();
        }
    }

    // drain: h2_511 = tanh(b2 + Wih2@h1_511 + Whh2@h2_510); both sit in hb[0].
    // wave 0 harmlessly computes a dead h1_512 into hb[1][0].
    {
        float* d0 = (wid == 0) ? w_e0 : &sfin[own0];
        do_step(512, 0, r_e, d0, w_e1);
    }
    __syncthreads();

    // ---- epilogue: LN -> proj+tanh -> LN, single wave, shfl reductions only
    if (wid == 0) {
        float v0 = sfin[lane], v1 = sfin[lane + 64];
        float sa = v0 + v1, sb = v0 * v0 + v1 * v1;
#pragma unroll
        for (int k = 32; k > 0; k >>= 1) { sa += __shfl_xor(sa, k); sb += __shfl_xor(sb, k); }
        float mu  = sa * (1.f / 128.f);
        float var = sb * (1.f / 128.f) - mu * mu;
        float rs  = rsqrtf(var + 1e-5f);
        float n0 = (v0 - mu) * rs * ln_g[lane] + ln_b[lane];
        float n1 = (v1 - mu) * rs * ln_g[lane + 64] + ln_b[lane + 64];
        sfin[lane] = n0; sfin[lane + 64] = n1;
        asm volatile("s_waitcnt lgkmcnt(0)" ::: "memory");   // LDS writes retired (same wave)
        float A0 = proj_b[lane],      A1 = 0.f, A2 = 0.f, A3 = 0.f;
        float C0 = proj_b[lane + 64], C1 = 0.f, C2 = 0.f, C3 = 0.f;
        const float4* hp4 = (const float4*)sfin;
        const float4* p0 = (const float4*)(projW + (size_t)lane * HID);
        const float4* p1 = (const float4*)(projW + (size_t)(lane + 64) * HID);
#pragma unroll
        for (int k = 0; k < 32; ++k) {
            float4 h4 = hp4[k], u = p0[k], w = p1[k];
            A0 = fmaf(h4.x, u.x, A0); A1 = fmaf(h4.y, u.y, A1);
            A2 = fmaf(h4.z, u.z, A2); A3 = fmaf(h4.w, u.w, A3);
            C0 = fmaf(h4.x, w.x, C0); C1 = fmaf(h4.y, w.y, C1);
            C2 = fmaf(h4.z, w.z, C2); C3 = fmaf(h4.w, w.w, C3);
        }
        float pv0 = tanhf((A0 + A1) + (A2 + A3));
        float pv1 = tanhf((C0 + C1) + (C2 + C3));
        float ta = pv0 + pv1, tb = pv0 * pv0 + pv1 * pv1;
#pragma unroll
        for (int k = 32; k > 0; k >>= 1) { ta += __shfl_xor(ta, k); tb += __shfl_xor(tb, k); }
        float mu2  = ta * (1.f / 128.f);
        float var2 = tb * (1.f / 128.f) - mu2 * mu2;
        float rs2  = rsqrtf(var2 + 1e-5f);
        out[(size_t)bb * HID + lane]      = (pv0 - mu2) * rs2 * on_g[lane] + on_b[lane];
        out[(size_t)bb * HID + lane + 64] = (pv1 - mu2) * rs2 * on_g[lane + 64] + on_b[lane + 64];
    }
}

extern "C" void kernel_launch(void* const* d_in, const int* in_sizes, int n_in,
                              void* d_out, int out_size, void* d_ws, size_t ws_size,
                              hipStream_t stream)
{
    const int*   x     = (const int*)  d_in[0];
    const float* emb   = (const float*)d_in[1];
    const float* Wih1  = (const float*)d_in[2];
    const float* bih1  = (const float*)d_in[3];
    const float* Whh1  = (const float*)d_in[4];
    const float* bhh1  = (const float*)d_in[5];
    const float* Wih2  = (const float*)d_in[6];
    const float* bih2  = (const float*)d_in[7];
    const float* Whh2  = (const float*)d_in[8];
    const float* bhh2  = (const float*)d_in[9];
    const float* ln_g  = (const float*)d_in[10];
    const float* ln_b  = (const float*)d_in[11];
    const float* projW = (const float*)d_in[12];
    const float* projb = (const float*)d_in[13];
    const float* on_g  = (const float*)d_in[14];
    const float* on_b  = (const float*)d_in[15];

    float* pre1 = (float*)d_ws;   // 64 MiB fp32

    k_embed_pre1<<<BT / 128, 256, 0, stream>>>(x, emb, Wih1, bih1, bhh1, pre1);
    k_rnn_fused<<<256, 192, 0, stream>>>(pre1, Whh1, Wih2, bih2, bhh2, Whh2,
                                         ln_g, ln_b, projW, projb, on_g, on_b,
                                         (float*)d_out);
}

// Round 2
// 447.945 us; speedup vs baseline: 1.2754x; 1.2754x over previous
//
#include <hip/hip_runtime.h>

#define BT (256*512)   // 131072 positions
#define HID 128
#define EMB 64
#define CH 32          // scan chunk: steps staged per LDS refill

__device__ __forceinline__ float fast_tanh(float x) {   // 1 - 2/(exp(2x)+1)
    float e = __expf(2.f * x);
    return 1.f - __fdividef(2.f, e + 1.f);
}

// pin a float4 (compiler may park in AGPR; scalar v_fma can source it) — proven recipe
#define OPQ(v) asm volatile("" : "+v"(v.x), "+v"(v.y), "+v"(v.z), "+v"(v.w))

// DPP butterfly add. ctrls: 0xB1 = quad_perm xor1, 0x4E = quad_perm xor2,
// 0x141 = row_half_mirror (lane ^= 7 within 8), 0x140 = row_mirror (lane ^= 15 within 16).
#define DPPADD(v, ctrl) ((v) + __int_as_float(__builtin_amdgcn_mov_dpp(__float_as_int(v), (ctrl), 0xF, 0xF, false)))

// 4-row x 16-col dual-partial dot against hv0..hv3 (visible at expansion site)
#define RACC(P, Q, wa, wb, wc, wd) \
    P = fmaf(hv0.x, wa.x, P); Q = fmaf(hv0.y, wa.y, Q); \
    P = fmaf(hv0.z, wa.z, P); Q = fmaf(hv0.w, wa.w, Q); \
    P = fmaf(hv1.x, wb.x, P); Q = fmaf(hv1.y, wb.y, Q); \
    P = fmaf(hv1.z, wb.z, P); Q = fmaf(hv1.w, wb.w, Q); \
    P = fmaf(hv2.x, wc.x, P); Q = fmaf(hv2.y, wc.y, Q); \
    P = fmaf(hv2.z, wc.z, P); Q = fmaf(hv2.w, wc.w, Q); \
    P = fmaf(hv3.x, wd.x, P); Q = fmaf(hv3.y, wd.y, Q); \
    P = fmaf(hv3.z, wd.z, P); Q = fmaf(hv3.w, wd.w, Q);

// ---------------- kernel 1: embedding gather + layer-1 input GEMM (unchanged, proven)
__global__ __launch_bounds__(256)
__attribute__((amdgpu_waves_per_eu(1, 2)))
void k_embed_pre1(
    const int* __restrict__ x, const float* __restrict__ emb,
    const float* __restrict__ Wih1, const float* __restrict__ bih1,
    const float* __restrict__ bhh1, float* __restrict__ pre1)
{
    __shared__ float sA[32][128];
    __shared__ float sW[32][132];
    __shared__ int stok[128];
    const int tid = threadIdx.x;
    const int base = blockIdx.x * 128;
    const int tx = tid & 15, ty = tid >> 4;
    const int ox = tx * 8, py = ty * 8;
    const int pl = tid & 127, half = tid >> 7;
    if (tid < 128) stok[tid] = x[base + tid];
    float acc[8][8];
#pragma unroll
    for (int p = 0; p < 8; ++p)
#pragma unroll
        for (int o = 0; o < 8; ++o) acc[p][o] = 0.f;
    __syncthreads();
    const float4* ws = (const float4*)(Wih1 + (size_t)pl * EMB + half * 16);
    const float4* as = (const float4*)(emb + (size_t)stok[pl] * EMB + half * 16);
    float4 qw[2][4], qe[2][4];
#pragma unroll
    for (int kc = 0; kc < 2; ++kc)
#pragma unroll
        for (int k = 0; k < 4; ++k) {
            qw[kc][k] = ws[kc * 8 + k];
            qe[kc][k] = as[kc * 8 + k];
        }
    for (int kc = 0; kc < 2; ++kc) {
        {
            const int jb = half * 16;
#pragma unroll
            for (int k = 0; k < 4; ++k) {
                float4 q = qw[kc][k], e = qe[kc][k];
                sW[jb + 4*k + 0][pl] = q.x; sW[jb + 4*k + 1][pl] = q.y;
                sW[jb + 4*k + 2][pl] = q.z; sW[jb + 4*k + 3][pl] = q.w;
                sA[jb + 4*k + 0][pl] = e.x; sA[jb + 4*k + 1][pl] = e.y;
                sA[jb + 4*k + 2][pl] = e.z; sA[jb + 4*k + 3][pl] = e.w;
            }
        }
        __syncthreads();
#pragma unroll 4
        for (int j = 0; j < 32; ++j) {
            float4 a0 = *(const float4*)&sA[j][py];
            float4 a1 = *(const float4*)&sA[j][py + 4];
            float4 b0 = *(const float4*)&sW[j][ox];
            float4 b1 = *(const float4*)&sW[j][ox + 4];
            float av[8] = {a0.x,a0.y,a0.z,a0.w,a1.x,a1.y,a1.z,a1.w};
            float bv[8] = {b0.x,b0.y,b0.z,b0.w,b1.x,b1.y,b1.z,b1.w};
#pragma unroll
            for (int p = 0; p < 8; ++p)
#pragma unroll
                for (int o = 0; o < 8; ++o)
                    acc[p][o] = fmaf(av[p], bv[o], acc[p][o]);
        }
        __syncthreads();
    }
    float bo[8];
#pragma unroll
    for (int o = 0; o < 8; ++o) bo[o] = bih1[ox + o] + bhh1[ox + o];
#pragma unroll
    for (int p = 0; p < 8; ++p) {
        float* cp = pre1 + (size_t)(base + py + p) * HID + ox;
        *(float4*)cp       = make_float4(acc[p][0]+bo[0], acc[p][1]+bo[1], acc[p][2]+bo[2], acc[p][3]+bo[3]);
        *(float4*)(cp + 4) = make_float4(acc[p][4]+bo[4], acc[p][5]+bo[5], acc[p][6]+bo[6], acc[p][7]+bo[7]);
    }
}

// block-wide sum for 768 threads (12 waves); pass 0 from non-contributing lanes
__device__ inline float bsum768(float v, volatile float* sc, int tid) {
#pragma unroll
    for (int off = 32; off > 0; off >>= 1) v += __shfl_down(v, off, 64);
    __syncthreads();
    if ((tid & 63) == 0) sc[tid >> 6] = v;
    __syncthreads();
    float s = 0.f;
#pragma unroll
    for (int k = 0; k < 12; ++k) s += sc[k];
    return s;
}

// ---------------- kernel 2: fused two-layer recurrence, 12-wave in-wave-reduce form.
// waves 0-3 (L1): h1_t = tanh(pre1[t] + Whh1 @ h1_{t-1})
// waves 4-11(L2): h2_{t-1} = tanh(b2 + Wih2 @ h1_{t-1} + Whh2 @ h2_{t-2})  (lag-1)
// Each lane: 4 rows x 16 cols pinned (64 floats — baseline-proven footprint).
// All K-partials of a row live in one wave -> pure-DPP butterfly reduce
// (xor1, xor2, xor7 [, xor15 across the Wih2/Whh2 halves]).
// => no sp[] round-trip, no publisher phase, ONE barrier per step, all-fp32 h.
__global__ __launch_bounds__(768)
__attribute__((amdgpu_waves_per_eu(1, 3)))
void k_rnn_fused(
    const float* __restrict__ pre1, const float* __restrict__ Whh1,
    const float* __restrict__ Wih2, const float* __restrict__ bih2,
    const float* __restrict__ bhh2, const float* __restrict__ Whh2,
    const float* __restrict__ ln_g, const float* __restrict__ ln_b,
    const float* __restrict__ projW, const float* __restrict__ proj_b,
    const float* __restrict__ on_g, const float* __restrict__ on_b,
    float* __restrict__ out)
{
    // h layout: value i at word (i>>4)*20 + (i&15). The 8 column-eighths start at
    // words {0,20,40,60,80,100,120,140} ≡ banks {0,20,8,28,16,4,24,12} -> the 8
    // concurrent 16B reads hit 8 disjoint 4-bank groups: conflict-free ds_read_b128.
    __shared__ __align__(16) float h1[2][160];
    __shared__ __align__(16) float h2[2][160];
    __shared__ __align__(16) float spre[CH * HID];   // staged pre1 chunk (16 KB)
    __shared__ float sfin[HID];
    __shared__ float sc[12];

    const int bb   = blockIdx.x;
    const int tid  = threadIdx.x;
    const int w    = tid >> 6;
    const int lane = tid & 63;
    const bool L1  = (w < 4);
    const int  e   = lane & 7;                     // column-eighth: cols e*16 .. e*16+15
    const int  m   = L1 ? 0 : ((lane >> 3) & 1);   // L2: 0 = Wih2 (reads h1), 1 = Whh2 (reads h2)
    const int  rg  = L1 ? (lane >> 3) : (lane >> 4);
    const int  rowbase = L1 ? (32 * w + rg) : (16 * (w - 4) + rg);
    const int  rstep   = L1 ? 8 : 4;               // rows rowbase + rstep*k, k=0..3
    const float* wmat  = L1 ? Whh1 : (m ? Whh2 : Wih2);

    // ---- pin 4 rows x 16 cols of weights (16 float4 = 64 floats / lane)
    const float4* wr0 = (const float4*)(wmat + (size_t)(rowbase            ) * HID + e * 16);
    const float4* wr1 = (const float4*)(wmat + (size_t)(rowbase +     rstep) * HID + e * 16);
    const float4* wr2 = (const float4*)(wmat + (size_t)(rowbase + 2 * rstep) * HID + e * 16);
    const float4* wr3 = (const float4*)(wmat + (size_t)(rowbase + 3 * rstep) * HID + e * 16);
    float4 w0 = wr0[0], w1 = wr0[1], w2  = wr0[2], w3  = wr0[3],
           w4 = wr1[0], w5 = wr1[1], w6  = wr1[2], w7  = wr1[3],
           w8 = wr2[0], w9 = wr2[1], w10 = wr2[2], w11 = wr2[3],
           w12= wr3[0], w13= wr3[1], w14 = wr3[2], w15 = wr3[3];
    OPQ(w0);OPQ(w1);OPQ(w2);OPQ(w3);OPQ(w4);OPQ(w5);OPQ(w6);OPQ(w7);
    OPQ(w8);OPQ(w9);OPQ(w10);OPQ(w11);OPQ(w12);OPQ(w13);OPQ(w14);OPQ(w15);

    // publisher role: lanes e<4 (and for L2 only the m==0 half) write row rowbase+e*rstep
    const bool wr_en = L1 ? (e < 4) : (m == 0 && e < 4);
    const int  wrow  = rowbase + (e & 3) * rstep;
    const int  wword = ((wrow >> 4) * 20) + (wrow & 15);
    const float b2w  = (!L1 && wr_en) ? (bih2[wrow] + bhh2[wrow]) : 0.f;

    if (tid < 160) { h1[0][tid] = 0.f; h2[0][tid] = 0.f; }

    // parity-resolved pointers (even t reads [0] writes [1]; odd t flips)
    const float* srcb = (L1 || m == 0) ? &h1[0][0] : &h2[0][0];
    const float4* rp0 = (const float4*)(srcb + e * 20);
    const float4* rp1 = (const float4*)(srcb + 160 + e * 20);
    float* dstb = L1 ? &h1[0][0] : &h2[0][0];
    float* wp_e = dstb + 160 + wword;   // even step writes parity 1
    float* wp_o = dstb + wword;         // odd step writes parity 0

    const float4* gsrc = (const float4*)(pre1 + (size_t)bb * 512 * HID);
    float4* spv = (float4*)spre;
    float4 pf0, pf1;
    if (tid < 512) { pf0 = gsrc[tid]; pf1 = gsrc[tid + 512]; }
    __syncthreads();                    // h init visible

    auto do_step = [&](int t, int s, const float4* rp, float* wpt) {
        float4 hv0 = rp[0], hv1 = rp[1], hv2 = rp[2], hv3 = rp[3];
        float p0=0,q0=0,p1=0,q1=0,p2=0,q2=0,p3=0,q3=0;
        RACC(p0,q0, w0,w1,w2,w3)
        RACC(p1,q1, w4,w5,w6,w7)
        RACC(p2,q2, w8,w9,w10,w11)
        RACC(p3,q3, w12,w13,w14,w15)
        float s0 = p0+q0, s1 = p1+q1, s2 = p2+q2, s3 = p3+q3;
        s0 = DPPADD(s0, 0xB1); s1 = DPPADD(s1, 0xB1); s2 = DPPADD(s2, 0xB1); s3 = DPPADD(s3, 0xB1);
        s0 = DPPADD(s0, 0x4E); s1 = DPPADD(s1, 0x4E); s2 = DPPADD(s2, 0x4E); s3 = DPPADD(s3, 0x4E);
        s0 = DPPADD(s0, 0x141); s1 = DPPADD(s1, 0x141); s2 = DPPADD(s2, 0x141); s3 = DPPADD(s3, 0x141);
        if (!L1) {  // sum Wih2@h1 and Whh2@h2 halves (lanes ^15)
            s0 = DPPADD(s0, 0x140); s1 = DPPADD(s1, 0x140);
            s2 = DPPADD(s2, 0x140); s3 = DPPADD(s3, 0x140);
        }
        if (wr_en) {
            float ta = (e & 1) ? s1 : s0;
            float tb = (e & 1) ? s3 : s2;
            float v  = (e & 2) ? tb : ta;
            if (L1) *wpt = fast_tanh(spre[s * HID + wrow] + v);
            else    *wpt = (t > 0) ? fast_tanh(b2w + v) : 0.f;   // h2_{-1} = 0
        }
        __syncthreads();
    };

#pragma unroll 1
    for (int c = 0; c < 512 / CH; ++c) {
        if (tid < 512) { spv[tid] = pf0; spv[tid + 512] = pf1; }
        __syncthreads();
        if (c < 512 / CH - 1 && tid < 512) {   // prefetch next chunk under 32 steps
            pf0 = gsrc[(c + 1) * 1024 + tid];
            pf1 = gsrc[(c + 1) * 1024 + tid + 512];
        }
        const int t0 = c * CH;
#pragma unroll 1
        for (int s = 0; s < CH; s += 2) {
            do_step(t0 + s,     s,     rp0, wp_e);
            do_step(t0 + s + 1, s + 1, rp1, wp_o);
        }
    }

    // drain: h2_511 = tanh(b2 + Wih2@h1_511 + Whh2@h2_510); both live at parity 0.
    // L1 lanes compute a dead value into h1[1] (harmless).
    {
        float* wpD = L1 ? wp_e : &sfin[wrow];
        do_step(512, 0, rp0, wpD);
    }

    // ---- epilogue: LN -> proj+tanh -> LN (values on tid<128; all barrier)
    const int i = tid & 127;
    float hn = (tid < 128) ? sfin[i] : 0.f;
    float s1v = bsum768(hn, sc, tid);
    float s2v = bsum768(hn * hn, sc, tid);
    float mu = s1v * (1.f / 128.f);
    float var = s2v * (1.f / 128.f) - mu * mu;
    __syncthreads();
    if (tid < 128) spre[i] = (hn - mu) * rsqrtf(var + 1e-5f) * ln_g[i] + ln_b[i];
    __syncthreads();
    float pv = 0.f;
    if (tid < 128) {
        float a0 = proj_b[i], a1 = 0, a2 = 0, a3 = 0;
        const float4* hp = (const float4*)spre;
        const float4* pr = (const float4*)(projW + (size_t)i * HID);
#pragma unroll
        for (int k = 0; k < HID / 4; ++k) {
            float4 u = pr[k];
            float4 hv = hp[k];
            a0 = fmaf(hv.x, u.x, a0); a1 = fmaf(hv.y, u.y, a1);
            a2 = fmaf(hv.z, u.z, a2); a3 = fmaf(hv.w, u.w, a3);
        }
        pv = tanhf((a0 + a1) + (a2 + a3));
    }
    float t1 = bsum768(pv, sc, tid);
    float t2 = bsum768(pv * pv, sc, tid);
    float mu2 = t1 * (1.f / 128.f);
    float var2 = t2 * (1.f / 128.f) - mu2 * mu2;
    if (tid < 128)
        out[(size_t)bb * HID + i] = (pv - mu2) * rsqrtf(var2 + 1e-5f) * on_g[i] + on_b[i];
}

extern "C" void kernel_launch(void* const* d_in, const int* in_sizes, int n_in,
                              void* d_out, int out_size, void* d_ws, size_t ws_size,
                              hipStream_t stream)
{
    const int*   x     = (const int*)  d_in[0];
    const float* emb   = (const float*)d_in[1];
    const float* Wih1  = (const float*)d_in[2];
    const float* bih1  = (const float*)d_in[3];
    const float* Whh1  = (const float*)d_in[4];
    const float* bhh1  = (const float*)d_in[5];
    const float* Wih2  = (const float*)d_in[6];
    const float* bih2  = (const float*)d_in[7];
    const float* Whh2  = (const float*)d_in[8];
    const float* bhh2  = (const float*)d_in[9];
    const float* ln_g  = (const float*)d_in[10];
    const float* ln_b  = (const float*)d_in[11];
    const float* projW = (const float*)d_in[12];
    const float* projb = (const float*)d_in[13];
    const float* on_g  = (const float*)d_in[14];
    const float* on_b  = (const float*)d_in[15];

    float* pre1 = (float*)d_ws;   // 64 MiB fp32

    k_embed_pre1<<<BT / 128, 256, 0, stream>>>(x, emb, Wih1, bih1, bhh1, pre1);
    k_rnn_fused<<<256, 768, 0, stream>>>(pre1, Whh1, Wih2, bih2, bhh2, Whh2,
                                         ln_g, ln_b, projW, projb, on_g, on_b,
                                         (float*)d_out);
}

// Round 3
// 437.995 us; speedup vs baseline: 1.3044x; 1.0227x over previous
//
#include <hip/hip_runtime.h>

#define BT (256*512)   // 131072 positions
#define HID 128
#define EMB 64
#define CH 32          // scan chunk: steps staged per LDS refill

__device__ __forceinline__ float fast_tanh(float x) {   // 1 - 2/(exp(2x)+1)
    float e = __expf(2.f * x);
    return 1.f - __fdividef(2.f, e + 1.f);
}

// pin a float4 (prevents rematerialization)
#define OPQ(v) asm volatile("" : "+v"(v.x), "+v"(v.y), "+v"(v.z), "+v"(v.w))

// ---- exact-codegen MAC: one VOP2 each, all operands forced into arch VGPRs
#define FMAC(a, h, w) asm("v_fmac_f32 %0, %1, %2" : "+v"(a) : "v"(h), "v"(w))
#define VMUL(a, h, w) asm("v_mul_f32 %0, %1, %2" : "=v"(a) : "v"(h), "v"(w))
#define MAC4(hc, wa, wb, wcc, wd) \
    FMAC(s0, hc, wa); FMAC(s1, hc, wb); FMAC(s2, hc, wcc); FMAC(s3, hc, wd)

// ---- fused DPP butterfly reduce: 1 instr/stage/value, fixed order inside one
// asm block (dependent ops 4 apart; s_nop 1 covers VALU->DPP wait states at entry)
#define RED_STAGE(ctrl) \
    "v_add_f32_dpp %0, %0, %0 " ctrl " row_mask:0xf bank_mask:0xf\n\t" \
    "v_add_f32_dpp %1, %1, %1 " ctrl " row_mask:0xf bank_mask:0xf\n\t" \
    "v_add_f32_dpp %2, %2, %2 " ctrl " row_mask:0xf bank_mask:0xf\n\t" \
    "v_add_f32_dpp %3, %3, %3 " ctrl " row_mask:0xf bank_mask:0xf\n\t"
#define REDUCE_L1 asm("s_nop 1\n\t" \
    RED_STAGE("quad_perm:[1,0,3,2]") \
    RED_STAGE("quad_perm:[2,3,0,1]") \
    RED_STAGE("row_half_mirror") \
    : "+v"(s0), "+v"(s1), "+v"(s2), "+v"(s3))
#define REDUCE_L2 asm("s_nop 1\n\t" \
    RED_STAGE("quad_perm:[1,0,3,2]") \
    RED_STAGE("quad_perm:[2,3,0,1]") \
    RED_STAGE("row_half_mirror") \
    RED_STAGE("row_mirror") \
    : "+v"(s0), "+v"(s1), "+v"(s2), "+v"(s3))

// ---------------- kernel 1: embedding gather + layer-1 input GEMM (unchanged, proven)
__global__ __launch_bounds__(256)
__attribute__((amdgpu_waves_per_eu(1, 2)))
void k_embed_pre1(
    const int* __restrict__ x, const float* __restrict__ emb,
    const float* __restrict__ Wih1, const float* __restrict__ bih1,
    const float* __restrict__ bhh1, float* __restrict__ pre1)
{
    __shared__ float sA[32][128];
    __shared__ float sW[32][132];
    __shared__ int stok[128];
    const int tid = threadIdx.x;
    const int base = blockIdx.x * 128;
    const int tx = tid & 15, ty = tid >> 4;
    const int ox = tx * 8, py = ty * 8;
    const int pl = tid & 127, half = tid >> 7;
    if (tid < 128) stok[tid] = x[base + tid];
    float acc[8][8];
#pragma unroll
    for (int p = 0; p < 8; ++p)
#pragma unroll
        for (int o = 0; o < 8; ++o) acc[p][o] = 0.f;
    __syncthreads();
    const float4* ws = (const float4*)(Wih1 + (size_t)pl * EMB + half * 16);
    const float4* as = (const float4*)(emb + (size_t)stok[pl] * EMB + half * 16);
    float4 qw[2][4], qe[2][4];
#pragma unroll
    for (int kc = 0; kc < 2; ++kc)
#pragma unroll
        for (int k = 0; k < 4; ++k) {
            qw[kc][k] = ws[kc * 8 + k];
            qe[kc][k] = as[kc * 8 + k];
        }
    for (int kc = 0; kc < 2; ++kc) {
        {
            const int jb = half * 16;
#pragma unroll
            for (int k = 0; k < 4; ++k) {
                float4 q = qw[kc][k], e = qe[kc][k];
                sW[jb + 4*k + 0][pl] = q.x; sW[jb + 4*k + 1][pl] = q.y;
                sW[jb + 4*k + 2][pl] = q.z; sW[jb + 4*k + 3][pl] = q.w;
                sA[jb + 4*k + 0][pl] = e.x; sA[jb + 4*k + 1][pl] = e.y;
                sA[jb + 4*k + 2][pl] = e.z; sA[jb + 4*k + 3][pl] = e.w;
            }
        }
        __syncthreads();
#pragma unroll 4
        for (int j = 0; j < 32; ++j) {
            float4 a0 = *(const float4*)&sA[j][py];
            float4 a1 = *(const float4*)&sA[j][py + 4];
            float4 b0 = *(const float4*)&sW[j][ox];
            float4 b1 = *(const float4*)&sW[j][ox + 4];
            float av[8] = {a0.x,a0.y,a0.z,a0.w,a1.x,a1.y,a1.z,a1.w};
            float bv[8] = {b0.x,b0.y,b0.z,b0.w,b1.x,b1.y,b1.z,b1.w};
#pragma unroll
            for (int p = 0; p < 8; ++p)
#pragma unroll
                for (int o = 0; o < 8; ++o)
                    acc[p][o] = fmaf(av[p], bv[o], acc[p][o]);
        }
        __syncthreads();
    }
    float bo[8];
#pragma unroll
    for (int o = 0; o < 8; ++o) bo[o] = bih1[ox + o] + bhh1[ox + o];
#pragma unroll
    for (int p = 0; p < 8; ++p) {
        float* cp = pre1 + (size_t)(base + py + p) * HID + ox;
        *(float4*)cp       = make_float4(acc[p][0]+bo[0], acc[p][1]+bo[1], acc[p][2]+bo[2], acc[p][3]+bo[3]);
        *(float4*)(cp + 4) = make_float4(acc[p][4]+bo[4], acc[p][5]+bo[5], acc[p][6]+bo[6], acc[p][7]+bo[7]);
    }
}

// block-wide sum for 768 threads (12 waves); pass 0 from non-contributing lanes
__device__ inline float bsum768(float v, volatile float* sc, int tid) {
#pragma unroll
    for (int off = 32; off > 0; off >>= 1) v += __shfl_down(v, off, 64);
    __syncthreads();
    if ((tid & 63) == 0) sc[tid >> 6] = v;
    __syncthreads();
    float s = 0.f;
#pragma unroll
    for (int k = 0; k < 12; ++k) s += sc[k];
    return s;
}

// ---------------- kernel 2: fused two-layer recurrence, 12-wave in-wave-reduce form.
// waves 0-3 (L1): h1_t = tanh(pre1[t] + Whh1 @ h1_{t-1})
// waves 4-11(L2): h2_{t-1} = tanh(b2 + Wih2 @ h1_{t-1} + Whh2 @ h2_{t-2})  (lag-1)
// Round-3 change: MAC core and DPP reduce are exact inline asm (v_fmac_f32 /
// fused v_add_f32_dpp) so weights are guaranteed arch-VGPR-resident.
__global__ __launch_bounds__(768)
__attribute__((amdgpu_waves_per_eu(3)))
void k_rnn_fused(
    const float* __restrict__ pre1, const float* __restrict__ Whh1,
    const float* __restrict__ Wih2, const float* __restrict__ bih2,
    const float* __restrict__ bhh2, const float* __restrict__ Whh2,
    const float* __restrict__ ln_g, const float* __restrict__ ln_b,
    const float* __restrict__ projW, const float* __restrict__ proj_b,
    const float* __restrict__ on_g, const float* __restrict__ on_b,
    float* __restrict__ out)
{
    // h layout: value i at word (i>>4)*20 + (i&15). The 8 column-eighths start at
    // words {0,20,40,60,80,100,120,140} ≡ banks {0,20,8,28,16,4,24,12} -> the 8
    // concurrent 16B reads hit 8 disjoint 4-bank groups: conflict-free ds_read_b128.
    __shared__ __align__(16) float h1[2][160];
    __shared__ __align__(16) float h2[2][160];
    __shared__ __align__(16) float spre[CH * HID];   // staged pre1 chunk (16 KB)
    __shared__ float sfin[HID];
    __shared__ float sc[12];

    const int bb   = blockIdx.x;
    const int tid  = threadIdx.x;
    const int w    = tid >> 6;
    const int lane = tid & 63;
    const bool L1  = (w < 4);
    const int  e   = lane & 7;                     // column-eighth: cols e*16 .. e*16+15
    const int  m   = L1 ? 0 : ((lane >> 3) & 1);   // L2: 0 = Wih2 (reads h1), 1 = Whh2 (reads h2)
    const int  rg  = L1 ? (lane >> 3) : (lane >> 4);
    const int  rowbase = L1 ? (32 * w + rg) : (16 * (w - 4) + rg);
    const int  rstep   = L1 ? 8 : 4;               // rows rowbase + rstep*k, k=0..3
    const float* wmat  = L1 ? Whh1 : (m ? Whh2 : Wih2);

    // ---- 4 rows x 16 cols of weights in arch VGPRs (16 float4 = 64 floats / lane)
    const float4* wr0 = (const float4*)(wmat + (size_t)(rowbase            ) * HID + e * 16);
    const float4* wr1 = (const float4*)(wmat + (size_t)(rowbase +     rstep) * HID + e * 16);
    const float4* wr2 = (const float4*)(wmat + (size_t)(rowbase + 2 * rstep) * HID + e * 16);
    const float4* wr3 = (const float4*)(wmat + (size_t)(rowbase + 3 * rstep) * HID + e * 16);
    float4 w0 = wr0[0], w1 = wr0[1], w2  = wr0[2], w3  = wr0[3],
           w4 = wr1[0], w5 = wr1[1], w6  = wr1[2], w7  = wr1[3],
           w8 = wr2[0], w9 = wr2[1], w10 = wr2[2], w11 = wr2[3],
           w12= wr3[0], w13= wr3[1], w14 = wr3[2], w15 = wr3[3];
    OPQ(w0);OPQ(w1);OPQ(w2);OPQ(w3);OPQ(w4);OPQ(w5);OPQ(w6);OPQ(w7);
    OPQ(w8);OPQ(w9);OPQ(w10);OPQ(w11);OPQ(w12);OPQ(w13);OPQ(w14);OPQ(w15);

    // publisher role: lanes e<4 (and for L2 only the m==0 half) write row rowbase+e*rstep
    const bool wr_en = L1 ? (e < 4) : (m == 0 && e < 4);
    const int  wrow  = rowbase + (e & 3) * rstep;
    const int  wword = ((wrow >> 4) * 20) + (wrow & 15);
    const float b2w  = (!L1 && wr_en) ? (bih2[wrow] + bhh2[wrow]) : 0.f;

    if (tid < 160) { h1[0][tid] = 0.f; h2[0][tid] = 0.f; }

    // parity-resolved pointers (even t reads [0] writes [1]; odd t flips)
    const float* srcb = (L1 || m == 0) ? &h1[0][0] : &h2[0][0];
    const float4* rp0 = (const float4*)(srcb + e * 20);
    const float4* rp1 = (const float4*)(srcb + 160 + e * 20);
    float* dstb = L1 ? &h1[0][0] : &h2[0][0];
    float* wp_e = dstb + 160 + wword;   // even step writes parity 1
    float* wp_o = dstb + wword;         // odd step writes parity 0

    const float4* gsrc = (const float4*)(pre1 + (size_t)bb * 512 * HID);
    float4* spv = (float4*)spre;
    float4 pf0, pf1;
    if (tid < 512) { pf0 = gsrc[tid]; pf1 = gsrc[tid + 512]; }
    __syncthreads();                    // h init visible

    auto do_step = [&](int t, const float* spp, const float4* rp, float* wpt) {
        float4 hv0 = rp[0], hv1 = rp[1], hv2 = rp[2], hv3 = rp[3];
        float s0, s1, s2, s3;
        VMUL(s0, hv0.x, w0.x); VMUL(s1, hv0.x, w4.x);
        VMUL(s2, hv0.x, w8.x); VMUL(s3, hv0.x, w12.x);
        MAC4(hv0.y, w0.y, w4.y, w8.y, w12.y);
        MAC4(hv0.z, w0.z, w4.z, w8.z, w12.z);
        MAC4(hv0.w, w0.w, w4.w, w8.w, w12.w);
        MAC4(hv1.x, w1.x, w5.x, w9.x, w13.x);
        MAC4(hv1.y, w1.y, w5.y, w9.y, w13.y);
        MAC4(hv1.z, w1.z, w5.z, w9.z, w13.z);
        MAC4(hv1.w, w1.w, w5.w, w9.w, w13.w);
        MAC4(hv2.x, w2.x, w6.x, w10.x, w14.x);
        MAC4(hv2.y, w2.y, w6.y, w10.y, w14.y);
        MAC4(hv2.z, w2.z, w6.z, w10.z, w14.z);
        MAC4(hv2.w, w2.w, w6.w, w10.w, w14.w);
        MAC4(hv3.x, w3.x, w7.x, w11.x, w15.x);
        MAC4(hv3.y, w3.y, w7.y, w11.y, w15.y);
        MAC4(hv3.z, w3.z, w7.z, w11.z, w15.z);
        MAC4(hv3.w, w3.w, w7.w, w11.w, w15.w);
        if (L1) { REDUCE_L1; } else { REDUCE_L2; }
        if (wr_en) {
            float ta = (e & 1) ? s1 : s0;
            float tb = (e & 1) ? s3 : s2;
            float v  = (e & 2) ? tb : ta;
            if (L1) *wpt = fast_tanh(spp[wrow] + v);
            else    *wpt = (t > 0) ? fast_tanh(b2w + v) : 0.f;   // h2_{-1} = 0
        }
        __syncthreads();
    };

#pragma unroll 1
    for (int c = 0; c < 512 / CH; ++c) {
        if (tid < 512) { spv[tid] = pf0; spv[tid + 512] = pf1; }
        __syncthreads();
        if (c < 512 / CH - 1 && tid < 512) {   // prefetch next chunk under 32 steps
            pf0 = gsrc[(c + 1) * 1024 + tid];
            pf1 = gsrc[(c + 1) * 1024 + tid + 512];
        }
        const int t0 = c * CH;
        const float* spp = spre;
#pragma unroll 1
        for (int s = 0; s < CH; s += 2) {
            do_step(t0 + s,     spp,       rp0, wp_e);
            do_step(t0 + s + 1, spp + HID, rp1, wp_o);
            spp += 2 * HID;
        }
    }

    // drain: h2_511 = tanh(b2 + Wih2@h1_511 + Whh2@h2_510); both live at parity 0.
    // L1 lanes compute a dead value into h1[1] (harmless).
    {
        float* wpD = L1 ? wp_e : &sfin[wrow];
        do_step(512, spre, rp0, wpD);
    }

    // ---- epilogue: LN -> proj+tanh -> LN (values on tid<128; all barrier)
    const int i = tid & 127;
    float hn = (tid < 128) ? sfin[i] : 0.f;
    float s1v = bsum768(hn, sc, tid);
    float s2v = bsum768(hn * hn, sc, tid);
    float mu = s1v * (1.f / 128.f);
    float var = s2v * (1.f / 128.f) - mu * mu;
    __syncthreads();
    if (tid < 128) spre[i] = (hn - mu) * rsqrtf(var + 1e-5f) * ln_g[i] + ln_b[i];
    __syncthreads();
    float pv = 0.f;
    if (tid < 128) {
        float a0 = proj_b[i], a1 = 0, a2 = 0, a3 = 0;
        const float4* hp = (const float4*)spre;
        const float4* pr = (const float4*)(projW + (size_t)i * HID);
#pragma unroll
        for (int k = 0; k < HID / 4; ++k) {
            float4 u = pr[k];
            float4 hv = hp[k];
            a0 = fmaf(hv.x, u.x, a0); a1 = fmaf(hv.y, u.y, a1);
            a2 = fmaf(hv.z, u.z, a2); a3 = fmaf(hv.w, u.w, a3);
        }
        pv = tanhf((a0 + a1) + (a2 + a3));
    }
    float t1 = bsum768(pv, sc, tid);
    float t2 = bsum768(pv * pv, sc, tid);
    float mu2 = t1 * (1.f / 128.f);
    float var2 = t2 * (1.f / 128.f) - mu2 * mu2;
    if (tid < 128)
        out[(size_t)bb * HID + i] = (pv - mu2) * rsqrtf(var2 + 1e-5f) * on_g[i] + on_b[i];
}

extern "C" void kernel_launch(void* const* d_in, const int* in_sizes, int n_in,
                              void* d_out, int out_size, void* d_ws, size_t ws_size,
                              hipStream_t stream)
{
    const int*   x     = (const int*)  d_in[0];
    const float* emb   = (const float*)d_in[1];
    const float* Wih1  = (const float*)d_in[2];
    const float* bih1  = (const float*)d_in[3];
    const float* Whh1  = (const float*)d_in[4];
    const float* bhh1  = (const float*)d_in[5];
    const float* Wih2  = (const float*)d_in[6];
    const float* bih2  = (const float*)d_in[7];
    const float* Whh2  = (const float*)d_in[8];
    const float* bhh2  = (const float*)d_in[9];
    const float* ln_g  = (const float*)d_in[10];
    const float* ln_b  = (const float*)d_in[11];
    const float* projW = (const float*)d_in[12];
    const float* projb = (const float*)d_in[13];
    const float* on_g  = (const float*)d_in[14];
    const float* on_b  = (const float*)d_in[15];

    float* pre1 = (float*)d_ws;   // 64 MiB fp32

    k_embed_pre1<<<BT / 128, 256, 0, stream>>>(x, emb, Wih1, bih1, bhh1, pre1);
    k_rnn_fused<<<256, 768, 0, stream>>>(pre1, Whh1, Wih2, bih2, bhh2, Whh2,
                                         ln_g, ln_b, projW, projb, on_g, on_b,
                                         (float*)d_out);
}